// Round 5
// baseline (523.896 us; speedup 1.0000x reference)
//
#include <hip/hip_runtime.h>
#include <hip/hip_bf16.h>
#include <stdint.h>

#define IN_F 1024
#define OUT_F 1024
#define NG 8
#define KSPLINE 8192            // IN_F * NG
#define KDIM 9216               // KSPLINE + IN_F
#define M_ROWS 8192
#define LOG2E 1.4426950408889634f
// KC = 1.75 * sqrt(log2(e)) : basis = exp(-((xn-c)*1.75)^2) = 2^(-(xn*KC - c*KC)^2)
#define KC 2.1019642153762872f

using half4v = __attribute__((ext_vector_type(4))) _Float16;
using half8  = __attribute__((ext_vector_type(8))) _Float16;
using f32x4  = __attribute__((ext_vector_type(4))) float;

#define AS1 __attribute__((address_space(1)))
#define AS3 __attribute__((address_space(3)))

// ---------------- W = [spline_w | base_w] as f16, row-major (OUT_F x KDIM) ----
__global__ __launch_bounds__(256) void prep_w_kernel(
        const float* __restrict__ sw, const float* __restrict__ bw,
        _Float16* __restrict__ W) {
    int idx = blockIdx.x * 256 + threadIdx.x;   // one float4 per thread
    int o   = idx / 2304;                       // 2304 float4 per output row
    int k4  = idx - o * 2304;
    float4 v;
    if (k4 < 2048) v = ((const float4*)sw)[(size_t)o * 2048 + k4];
    else           v = ((const float4*)bw)[(size_t)o * 256 + (k4 - 2048)];
    half4v h = { (_Float16)v.x, (_Float16)v.y, (_Float16)v.z, (_Float16)v.w };  // RNE
    *(half4v*)(W + (size_t)idx * 4) = h;
}

// ---------------- LN -> xqT (transposed f16) + silu (row-major f16) -----------
// Block = 1024 threads = 16 waves = 16 consecutive rows. Per-wave LN stats via
// shfl; xq transposed through padded LDS (stride 20 words -> float4-aligned,
// conflict-light) so xqT stores are 16B/thread, contiguous across lanes.
__global__ __launch_bounds__(1024) void prep_ln_kernel(
        const float* __restrict__ x, const float* __restrict__ gamma,
        const float* __restrict__ beta, _Float16* __restrict__ xqT,
        _Float16* __restrict__ silu) {
    __shared__ float lds[512 * 20];   // 40 KB
    const int w = threadIdx.x >> 6, lane = threadIdx.x & 63;
    const int rowbase = blockIdx.x * 16;
    const int row = rowbase + w;
    const float* xr = x + (size_t)row * IN_F;

    float xv[16];
    float s = 0.0f, s2 = 0.0f;
#pragma unroll
    for (int j = 0; j < 16; ++j) {
        float v = xr[j * 64 + lane];
        xv[j] = v;
        s += v;
        s2 += v * v;
    }
#pragma unroll
    for (int off = 32; off > 0; off >>= 1) {
        s  += __shfl_xor(s, off);
        s2 += __shfl_xor(s2, off);
    }
    float mu   = s * (1.0f / IN_F);
    float var  = s2 * (1.0f / IN_F) - mu * mu;
    float rstd = rsqrtf(var + 1e-5f);

    // silu, row-major (independent of LDS passes)
    _Float16* srow = silu + (size_t)row * IN_F;
#pragma unroll
    for (int j = 0; j < 16; ++j) {
        int f = j * 64 + lane;
        float xs = xv[j];
        srow[f] = (_Float16)(xs / (1.0f + exp2f(-xs * LOG2E)));
    }

    // xq transpose: two half-passes of 512 features through LDS
#pragma unroll
    for (int p = 0; p < 2; ++p) {
        __syncthreads();    // protect previous pass's drain reads
#pragma unroll
        for (int j2 = 0; j2 < 8; ++j2) {
            int j = p * 8 + j2;
            int f = j * 64 + lane;
            float xn = (xv[j] - mu) * rstd * gamma[f] + beta[f];
            lds[(j2 * 64 + lane) * 20 + w] = xn * KC;
        }
        __syncthreads();
        int t  = threadIdx.x;
        int fl = t >> 1;                 // 0..511
        int rh = (t & 1) * 8;            // row half
        float4 v0 = *(const float4*)(lds + fl * 20 + rh);
        float4 v1 = *(const float4*)(lds + fl * 20 + rh + 4);
        half8 h = { (_Float16)v0.x, (_Float16)v0.y, (_Float16)v0.z, (_Float16)v0.w,
                    (_Float16)v1.x, (_Float16)v1.y, (_Float16)v1.z, (_Float16)v1.w };
        *(half8*)(xqT + (size_t)(p * 512 + fl) * M_ROWS + rowbase + rh) = h;
    }
}

// ---------------- Fused GEMM: C = [basis(xq) | silu] * W^T + bias -------------
// Spline ktiles: A-fragments generated in-register (lane's fragment = 8 grid
// points of ONE feature: k=(lane>>4)*8+j -> feat=kt*4+(lane>>4), g=j). Only W
// staged through LDS (8 KB/ktile barrier drain, half of before). Base ktiles:
// silu staged via global_load_lds as in the verified m97 path.
__global__ __launch_bounds__(256, 2) void gemm_fused_kernel(
        const _Float16* __restrict__ xqT, const _Float16* __restrict__ silu,
        const _Float16* __restrict__ W, const float* __restrict__ bias,
        float* __restrict__ C) {
    __shared__ alignas(16) _Float16 As[128 * 32];   // 8 KB (base part only)
    __shared__ alignas(16) _Float16 Bs[128 * 32];   // 8 KB
    const int bm = blockIdx.x, bn = blockIdx.y;
    const int tid = threadIdx.x;
    const int wave = tid >> 6, lane = tid & 63;
    const int wm = wave >> 1, wn = wave & 1;

    f32x4 acc[4][4] = {};

    const _Float16* gB[2];
    const _Float16* gAb[2];
    int ldsOff[2];
#pragma unroll
    for (int j = 0; j < 2; ++j) {
        int chunk = wave * 128 + j * 64 + lane;    // 0..511
        int r  = chunk >> 2;
        int c8 = (chunk & 3) * 8;
        gB[j]  = W    + (size_t)(bn * 128 + r) * KDIM + c8;
        gAb[j] = silu + (size_t)(bm * 128 + r) * IN_F + c8;
        ldsOff[j] = chunk * 8;
    }

    const int lm = lane & 15;
    const int lk = (lane >> 4) * 8;

    const float cq[8] = {
        -2.0000000f * KC, -1.4285715f * KC, -0.8571429f * KC, -0.2857143f * KC,
         0.2857143f * KC,  0.8571429f * KC,  1.4285715f * KC,  2.0000000f * KC };

    // lane's xq stream: feat = kt*4 + (lane>>4), row = bm*128 + wm*64 + mi*16 + lm
    const _Float16* xqp = xqT + (size_t)(lane >> 4) * M_ROWS
                              + (size_t)bm * 128 + wm * 64 + lm;

    for (int kt = 0; kt < KSPLINE / 32; ++kt) {
        __syncthreads();
#pragma unroll
        for (int j = 0; j < 2; ++j)
            __builtin_amdgcn_global_load_lds(
                (const AS1 void*)(gB[j] + kt * 32), (AS3 void*)(Bs + ldsOff[j]), 16, 0, 0);
        float xqv[4];
#pragma unroll
        for (int mi = 0; mi < 4; ++mi)
            xqv[mi] = (float)xqp[(size_t)kt * 4 * M_ROWS + mi * 16];
        __syncthreads();

        half8 b[4];
#pragma unroll
        for (int i = 0; i < 4; ++i)
            b[i] = *(const half8*)(Bs + (wn * 64 + i * 16 + lm) * 32 + lk);

        half8 a[4];
#pragma unroll
        for (int mi = 0; mi < 4; ++mi) {
            float q = xqv[mi];
            half8 h;
#pragma unroll
            for (int g = 0; g < 8; ++g) {
                float v = q - cq[g];
                h[g] = (_Float16)exp2f(-(v * v));
            }
            a[mi] = h;
        }

#pragma unroll
        for (int mi = 0; mi < 4; ++mi)
#pragma unroll
            for (int ni = 0; ni < 4; ++ni)
                acc[mi][ni] = __builtin_amdgcn_mfma_f32_16x16x32_f16(
                    a[mi], b[ni], acc[mi][ni], 0, 0, 0);
    }

    // base part: k = 8192 .. 9215, silu staged through As
    for (int kt = 0; kt < IN_F / 32; ++kt) {
        __syncthreads();
#pragma unroll
        for (int j = 0; j < 2; ++j) {
            __builtin_amdgcn_global_load_lds(
                (const AS1 void*)(gAb[j] + kt * 32), (AS3 void*)(As + ldsOff[j]), 16, 0, 0);
            __builtin_amdgcn_global_load_lds(
                (const AS1 void*)(gB[j] + KSPLINE + kt * 32), (AS3 void*)(Bs + ldsOff[j]), 16, 0, 0);
        }
        __syncthreads();

        half8 a[4], b[4];
#pragma unroll
        for (int i = 0; i < 4; ++i) {
            a[i] = *(const half8*)(As + (wm * 64 + i * 16 + lm) * 32 + lk);
            b[i] = *(const half8*)(Bs + (wn * 64 + i * 16 + lm) * 32 + lk);
        }
#pragma unroll
        for (int mi = 0; mi < 4; ++mi)
#pragma unroll
            for (int ni = 0; ni < 4; ++ni)
                acc[mi][ni] = __builtin_amdgcn_mfma_f32_16x16x32_f16(
                    a[mi], b[ni], acc[mi][ni], 0, 0, 0);
    }

    // epilogue: C/D layout col = lane&15, row = (lane>>4)*4 + reg
    const int cn = lane & 15;
    const int rm = (lane >> 4) * 4;
#pragma unroll
    for (int ni = 0; ni < 4; ++ni) {
        int col = bn * 128 + wn * 64 + ni * 16 + cn;
        float bv = bias[col];
#pragma unroll
        for (int mi = 0; mi < 4; ++mi) {
            int row = bm * 128 + wm * 64 + mi * 16 + rm;
            float* Cp = C + (size_t)row * OUT_F + col;
#pragma unroll
            for (int r = 0; r < 4; ++r)
                Cp[(size_t)r * OUT_F] = acc[mi][ni][r] + bv;
        }
    }
}

extern "C" void kernel_launch(void* const* d_in, const int* in_sizes, int n_in,
                              void* d_out, int out_size, void* d_ws, size_t ws_size,
                              hipStream_t stream) {
    const float* x     = (const float*)d_in[0];
    const float* gamma = (const float*)d_in[1];
    const float* beta  = (const float*)d_in[2];
    const float* sw    = (const float*)d_in[3];
    const float* bw    = (const float*)d_in[4];
    const float* bb    = (const float*)d_in[5];
    float* out = (float*)d_out;

    char* ws = (char*)d_ws;
    _Float16* Wb   = (_Float16*)ws;                                   // 18.9 MB
    _Float16* xqT  = (_Float16*)(ws + (size_t)OUT_F * KDIM * 2);      // 16.8 MB
    _Float16* silu = (_Float16*)(ws + (size_t)OUT_F * KDIM * 2
                                    + (size_t)IN_F * M_ROWS * 2);     // 16.8 MB

    prep_w_kernel<<<(OUT_F * 2304) / 256, 256, 0, stream>>>(sw, bw, Wb);
    prep_ln_kernel<<<M_ROWS / 16, 1024, 0, stream>>>(x, gamma, beta, xqT, silu);
    gemm_fused_kernel<<<dim3(M_ROWS / 128, OUT_F / 128), 256, 0, stream>>>(
        xqT, silu, Wb, bb, out);
}

// Round 6
// 324.856 us; speedup vs baseline: 1.6127x; 1.6127x over previous
//
#include <hip/hip_runtime.h>
#include <hip/hip_bf16.h>
#include <stdint.h>

#define IN_F 1024
#define OUT_F 1024
#define NG 8
#define KSPLINE 8192            // IN_F * NG
#define KDIM 9216               // KSPLINE + IN_F
#define M_ROWS 8192
#define LOG2E 1.4426950408889634f
// KC = 1.75 * sqrt(log2(e)) : basis = exp(-((xn-c)*1.75)^2) = 2^(-(xn*KC - c*KC)^2)
#define KC 2.1019642153762872f

#define A_BLOCKS (M_ROWS / 4)           // 2048 (4 rows per block, wave-per-row)
#define W_BLOCKS ((OUT_F * 2304) / 256) // 9216

using half4v = __attribute__((ext_vector_type(4))) _Float16;
using half8  = __attribute__((ext_vector_type(8))) _Float16;
using f32x4  = __attribute__((ext_vector_type(4))) float;

#define AS1 __attribute__((address_space(1)))
#define AS3 __attribute__((address_space(3)))

// ---- merged prep: blocks [0, A_BLOCKS) build A; [A_BLOCKS, +W_BLOCKS) build W
// A = [rbf_basis(LN(x)) | silu(x)] f16 row-major (M_ROWS x KDIM).
// One wave per row: no LDS, no syncthreads; lane handles f = j*64+lane so each
// 16B basis store is 1KB lane-contiguous.
// W = [spline_w | base_w] f16 row-major (OUT_F x KDIM).
__global__ __launch_bounds__(256) void prep_kernel(
        const float* __restrict__ x, const float* __restrict__ gamma,
        const float* __restrict__ beta, const float* __restrict__ sw,
        const float* __restrict__ bw, _Float16* __restrict__ A,
        _Float16* __restrict__ W) {
    if (blockIdx.x >= A_BLOCKS) {
        int idx = (blockIdx.x - A_BLOCKS) * 256 + threadIdx.x;  // one float4 each
        int o   = idx / 2304;
        int k4  = idx - o * 2304;
        float4 v;
        if (k4 < 2048) v = ((const float4*)sw)[(size_t)o * 2048 + k4];
        else           v = ((const float4*)bw)[(size_t)o * 256 + (k4 - 2048)];
        half4v h = { (_Float16)v.x, (_Float16)v.y, (_Float16)v.z, (_Float16)v.w };
        *(half4v*)(W + (size_t)idx * 4) = h;
        return;
    }
    const int wave = threadIdx.x >> 6, lane = threadIdx.x & 63;
    const int row = blockIdx.x * 4 + wave;
    const float* xr = x + (size_t)row * IN_F;

    float xv[16];
    float s = 0.0f, s2 = 0.0f;
#pragma unroll
    for (int j = 0; j < 16; ++j) {
        float v = xr[j * 64 + lane];
        xv[j] = v;
        s += v;
        s2 += v * v;
    }
#pragma unroll
    for (int off = 32; off > 0; off >>= 1) {
        s  += __shfl_xor(s, off);
        s2 += __shfl_xor(s2, off);
    }
    float mu   = s * (1.0f / IN_F);
    float var  = s2 * (1.0f / IN_F) - mu * mu;
    float rstd = rsqrtf(var + 1e-5f);

    const float cq[8] = {
        -2.0000000f * KC, -1.4285715f * KC, -0.8571429f * KC, -0.2857143f * KC,
         0.2857143f * KC,  0.8571429f * KC,  1.4285715f * KC,  2.0000000f * KC };

    _Float16* Arow = A + (size_t)row * KDIM;
    half8* basis_out = (half8*)Arow;                       // chunk f = feature f
    _Float16* silu_out = Arow + KSPLINE;
#pragma unroll
    for (int j = 0; j < 16; ++j) {
        int f = j * 64 + lane;
        float xs = xv[j];
        float xq = ((xs - mu) * rstd * gamma[f] + beta[f]) * KC;
        half8 h;
#pragma unroll
        for (int g = 0; g < 8; ++g) {
            float v = xq - cq[g];
            h[g] = (_Float16)exp2f(-(v * v));
        }
        basis_out[f] = h;
        silu_out[f] = (_Float16)(xs / (1.0f + exp2f(-xs * LOG2E)));
    }
}

// ---------------- GEMM: C(rows x 1024) = A(rows x 9216) * W^T + bias ----------
// m97 structure: 128x128 tile, BK=32, 4 waves each 64x64 via 4x4 mfma 16x16x32.
__global__ __launch_bounds__(256, 2) void gemm_kernel(
        const _Float16* __restrict__ A, const _Float16* __restrict__ W,
        const float* __restrict__ bias, float* __restrict__ C) {
    __shared__ alignas(16) _Float16 As[128 * 32];   // 8 KB
    __shared__ alignas(16) _Float16 Bs[128 * 32];   // 8 KB
    const int bm = blockIdx.x, bn = blockIdx.y;
    const int tid = threadIdx.x;
    const int wave = tid >> 6, lane = tid & 63;
    const int wm = wave >> 1, wn = wave & 1;

    f32x4 acc[4][4] = {};

    // staging: 8192 B per tile = 512 x 16B chunks; each wave 2 issues of 64 lanes
    const _Float16* gAj[2];
    const _Float16* gBj[2];
    int ldsOff[2];
#pragma unroll
    for (int j = 0; j < 2; ++j) {
        int chunk = wave * 128 + j * 64 + lane;    // 0..511
        int r  = chunk >> 2;                       // tile row 0..127
        int c8 = (chunk & 3) * 8;                  // k-offset in elements
        gAj[j] = A + (size_t)(bm * 128 + r) * KDIM + c8;
        gBj[j] = W + (size_t)(bn * 128 + r) * KDIM + c8;
        ldsOff[j] = chunk * 8;                     // element offset in LDS tile
    }

    const int lm = lane & 15;
    const int lk = (lane >> 4) * 8;

    for (int kt = 0; kt < KDIM / 32; ++kt) {
        __syncthreads();   // previous iter's ds_reads done before overwrite
#pragma unroll
        for (int j = 0; j < 2; ++j) {
            __builtin_amdgcn_global_load_lds(
                (const AS1 void*)(gAj[j] + kt * 32), (AS3 void*)(As + ldsOff[j]), 16, 0, 0);
            __builtin_amdgcn_global_load_lds(
                (const AS1 void*)(gBj[j] + kt * 32), (AS3 void*)(Bs + ldsOff[j]), 16, 0, 0);
        }
        __syncthreads();   // staging complete

        half8 a[4], b[4];
#pragma unroll
        for (int i = 0; i < 4; ++i) {
            a[i] = *(const half8*)(As + (wm * 64 + i * 16 + lm) * 32 + lk);
            b[i] = *(const half8*)(Bs + (wn * 64 + i * 16 + lm) * 32 + lk);
        }
#pragma unroll
        for (int mi = 0; mi < 4; ++mi)
#pragma unroll
            for (int ni = 0; ni < 4; ++ni)
                acc[mi][ni] = __builtin_amdgcn_mfma_f32_16x16x32_f16(
                    a[mi], b[ni], acc[mi][ni], 0, 0, 0);
    }

    // epilogue: C/D layout col = lane&15, row = (lane>>4)*4 + reg
    const int cn = lane & 15;
    const int rm = (lane >> 4) * 4;
#pragma unroll
    for (int ni = 0; ni < 4; ++ni) {
        int col = bn * 128 + wn * 64 + ni * 16 + cn;
        float bv = bias[col];
#pragma unroll
        for (int mi = 0; mi < 4; ++mi) {
            int row = bm * 128 + wm * 64 + mi * 16 + rm;
            float* Cp = C + (size_t)row * OUT_F + col;
#pragma unroll
            for (int r = 0; r < 4; ++r)
                Cp[(size_t)r * OUT_F] = acc[mi][ni][r] + bv;
        }
    }
}

extern "C" void kernel_launch(void* const* d_in, const int* in_sizes, int n_in,
                              void* d_out, int out_size, void* d_ws, size_t ws_size,
                              hipStream_t stream) {
    const float* x     = (const float*)d_in[0];
    const float* gamma = (const float*)d_in[1];
    const float* beta  = (const float*)d_in[2];
    const float* sw    = (const float*)d_in[3];
    const float* bw    = (const float*)d_in[4];
    const float* bb    = (const float*)d_in[5];
    float* out = (float*)d_out;

    char* ws = (char*)d_ws;
    _Float16* Wb = (_Float16*)ws;                                 // 18.9 MB
    _Float16* Ab = (_Float16*)(ws + (size_t)OUT_F * KDIM * 2);    // 151 MB

    prep_kernel<<<A_BLOCKS + W_BLOCKS, 256, 0, stream>>>(
        x, gamma, beta, sw, bw, Ab, Wb);
    gemm_kernel<<<dim3(M_ROWS / 128, OUT_F / 128), 256, 0, stream>>>(
        Ab, Wb, bb, out);
}

// Round 7
// 302.857 us; speedup vs baseline: 1.7298x; 1.0726x over previous
//
#include <hip/hip_runtime.h>
#include <hip/hip_bf16.h>
#include <stdint.h>

#define IN_F 1024
#define OUT_F 1024
#define NG 8
#define KSPLINE 8192            // IN_F * NG
#define KDIM 9216               // KSPLINE + IN_F
#define M_ROWS 8192
#define LOG2E 1.4426950408889634f
// KC = 1.75 * sqrt(log2(e)) : basis = exp(-((xn-c)*1.75)^2) = 2^(-(xn*KC - c*KC)^2)
#define KC 2.1019642153762872f

#define A_BLOCKS (M_ROWS / 4)           // 2048 (4 rows per block, wave-per-row)
#define W_BLOCKS ((OUT_F * 2304) / 256) // 9216

using half4v = __attribute__((ext_vector_type(4))) _Float16;
using half8  = __attribute__((ext_vector_type(8))) _Float16;
using f32x4  = __attribute__((ext_vector_type(4))) float;

#define AS1 __attribute__((address_space(1)))
#define AS3 __attribute__((address_space(3)))

// ---- merged prep: blocks [0, A_BLOCKS) build A; [A_BLOCKS, +W_BLOCKS) build W
__global__ __launch_bounds__(256) void prep_kernel(
        const float* __restrict__ x, const float* __restrict__ gamma,
        const float* __restrict__ beta, const float* __restrict__ sw,
        const float* __restrict__ bw, _Float16* __restrict__ A,
        _Float16* __restrict__ W) {
    if (blockIdx.x >= A_BLOCKS) {
        int idx = (blockIdx.x - A_BLOCKS) * 256 + threadIdx.x;  // one float4 each
        int o   = idx / 2304;
        int k4  = idx - o * 2304;
        float4 v;
        if (k4 < 2048) v = ((const float4*)sw)[(size_t)o * 2048 + k4];
        else           v = ((const float4*)bw)[(size_t)o * 256 + (k4 - 2048)];
        half4v h = { (_Float16)v.x, (_Float16)v.y, (_Float16)v.z, (_Float16)v.w };
        *(half4v*)(W + (size_t)idx * 4) = h;
        return;
    }
    const int wave = threadIdx.x >> 6, lane = threadIdx.x & 63;
    const int row = blockIdx.x * 4 + wave;
    const float* xr = x + (size_t)row * IN_F;

    float xv[16];
    float s = 0.0f, s2 = 0.0f;
#pragma unroll
    for (int j = 0; j < 16; ++j) {
        float v = xr[j * 64 + lane];
        xv[j] = v;
        s += v;
        s2 += v * v;
    }
#pragma unroll
    for (int off = 32; off > 0; off >>= 1) {
        s  += __shfl_xor(s, off);
        s2 += __shfl_xor(s2, off);
    }
    float mu   = s * (1.0f / IN_F);
    float var  = s2 * (1.0f / IN_F) - mu * mu;
    float rstd = rsqrtf(var + 1e-5f);

    const float cq[8] = {
        -2.0000000f * KC, -1.4285715f * KC, -0.8571429f * KC, -0.2857143f * KC,
         0.2857143f * KC,  0.8571429f * KC,  1.4285715f * KC,  2.0000000f * KC };

    _Float16* Arow = A + (size_t)row * KDIM;
    half8* basis_out = (half8*)Arow;                       // chunk f = feature f
    _Float16* silu_out = Arow + KSPLINE;
#pragma unroll
    for (int j = 0; j < 16; ++j) {
        int f = j * 64 + lane;
        float xs = xv[j];
        float xq = ((xs - mu) * rstd * gamma[f] + beta[f]) * KC;
        half8 h;
#pragma unroll
        for (int g = 0; g < 8; ++g) {
            float v = xq - cq[g];
            h[g] = (_Float16)exp2f(-(v * v));
        }
        basis_out[f] = h;
        silu_out[f] = (_Float16)(xs / (1.0f + exp2f(-xs * LOG2E)));
    }
}

// ---------------- GEMM: C(rows x 1024) = A(rows x 9216) * W^T + bias ----------
// m97 structure, 128x128 tile, but BK=64 per barrier pair: two 128x32
// sub-buffers per operand (same banking as the verified BK=32 layout),
// halving barrier-drain events 288 -> 144. LDS 32 KB, still 2 blocks/CU.
__global__ __launch_bounds__(256, 2) void gemm_kernel(
        const _Float16* __restrict__ A, const _Float16* __restrict__ W,
        const float* __restrict__ bias, float* __restrict__ C) {
    __shared__ alignas(16) _Float16 As[2][128 * 32];   // 16 KB
    __shared__ alignas(16) _Float16 Bs[2][128 * 32];   // 16 KB
    const int bm = blockIdx.x, bn = blockIdx.y;
    const int tid = threadIdx.x;
    const int wave = tid >> 6, lane = tid & 63;
    const int wm = wave >> 1, wn = wave & 1;

    f32x4 acc[4][4] = {};

    // staging: per 128x32 sub-tile = 512 x 16B chunks; each wave 2 issues
    const _Float16* gAj[2];
    const _Float16* gBj[2];
    int ldsOff[2];
#pragma unroll
    for (int j = 0; j < 2; ++j) {
        int chunk = wave * 128 + j * 64 + lane;    // 0..511
        int r  = chunk >> 2;                       // tile row 0..127
        int c8 = (chunk & 3) * 8;                  // k-offset in elements
        gAj[j] = A + (size_t)(bm * 128 + r) * KDIM + c8;
        gBj[j] = W + (size_t)(bn * 128 + r) * KDIM + c8;
        ldsOff[j] = chunk * 8;                     // element offset in LDS sub-tile
    }

    const int lm = lane & 15;
    const int lk = (lane >> 4) * 8;

    for (int kt = 0; kt < KDIM / 64; ++kt) {
        __syncthreads();   // previous iter's ds_reads done before overwrite
#pragma unroll
        for (int h = 0; h < 2; ++h)
#pragma unroll
            for (int j = 0; j < 2; ++j) {
                __builtin_amdgcn_global_load_lds(
                    (const AS1 void*)(gAj[j] + kt * 64 + h * 32),
                    (AS3 void*)(&As[h][0] + ldsOff[j]), 16, 0, 0);
                __builtin_amdgcn_global_load_lds(
                    (const AS1 void*)(gBj[j] + kt * 64 + h * 32),
                    (AS3 void*)(&Bs[h][0] + ldsOff[j]), 16, 0, 0);
            }
        __syncthreads();   // staging complete

#pragma unroll
        for (int h = 0; h < 2; ++h) {
            half8 a[4], b[4];
#pragma unroll
            for (int i = 0; i < 4; ++i) {
                a[i] = *(const half8*)(&As[h][0] + (wm * 64 + i * 16 + lm) * 32 + lk);
                b[i] = *(const half8*)(&Bs[h][0] + (wn * 64 + i * 16 + lm) * 32 + lk);
            }
#pragma unroll
            for (int mi = 0; mi < 4; ++mi)
#pragma unroll
                for (int ni = 0; ni < 4; ++ni)
                    acc[mi][ni] = __builtin_amdgcn_mfma_f32_16x16x32_f16(
                        a[mi], b[ni], acc[mi][ni], 0, 0, 0);
        }
    }

    // epilogue: C/D layout col = lane&15, row = (lane>>4)*4 + reg
    const int cn = lane & 15;
    const int rm = (lane >> 4) * 4;
#pragma unroll
    for (int ni = 0; ni < 4; ++ni) {
        int col = bn * 128 + wn * 64 + ni * 16 + cn;
        float bv = bias[col];
#pragma unroll
        for (int mi = 0; mi < 4; ++mi) {
            int row = bm * 128 + wm * 64 + mi * 16 + rm;
            float* Cp = C + (size_t)row * OUT_F + col;
#pragma unroll
            for (int r = 0; r < 4; ++r)
                Cp[(size_t)r * OUT_F] = acc[mi][ni][r] + bv;
        }
    }
}

extern "C" void kernel_launch(void* const* d_in, const int* in_sizes, int n_in,
                              void* d_out, int out_size, void* d_ws, size_t ws_size,
                              hipStream_t stream) {
    const float* x     = (const float*)d_in[0];
    const float* gamma = (const float*)d_in[1];
    const float* beta  = (const float*)d_in[2];
    const float* sw    = (const float*)d_in[3];
    const float* bw    = (const float*)d_in[4];
    const float* bb    = (const float*)d_in[5];
    float* out = (float*)d_out;

    char* ws = (char*)d_ws;
    _Float16* Wb = (_Float16*)ws;                                 // 18.9 MB
    _Float16* Ab = (_Float16*)(ws + (size_t)OUT_F * KDIM * 2);    // 151 MB

    prep_kernel<<<A_BLOCKS + W_BLOCKS, 256, 0, stream>>>(
        x, gamma, beta, sw, bw, Ab, Wb);
    gemm_kernel<<<dim3(M_ROWS / 128, OUT_F / 128), 256, 0, stream>>>(
        Ab, Wb, bb, out);
}

// Round 8
// 294.278 us; speedup vs baseline: 1.7803x; 1.0292x over previous
//
#include <hip/hip_runtime.h>
#include <hip/hip_bf16.h>
#include <stdint.h>

#define IN_F 1024
#define OUT_F 1024
#define NG 8
#define KSPLINE 8192            // IN_F * NG
#define KDIM 9216               // KSPLINE + IN_F
#define M_ROWS 8192
#define LOG2E 1.4426950408889634f
// KC = 1.75 * sqrt(log2(e)) : basis = exp(-((xn-c)*1.75)^2) = 2^(-(xn*KC - c*KC)^2)
#define KC 2.1019642153762872f

#define A_BLOCKS (M_ROWS / 4)           // 2048 (4 rows per block, wave-per-row)
#define W_BLOCKS ((OUT_F * 2304) / 256) // 9216

using half4v = __attribute__((ext_vector_type(4))) _Float16;
using half8  = __attribute__((ext_vector_type(8))) _Float16;
using f32x4  = __attribute__((ext_vector_type(4))) float;

#define AS1 __attribute__((address_space(1)))
#define AS3 __attribute__((address_space(3)))

// ---- merged prep: blocks [0, A_BLOCKS) build A; [A_BLOCKS, +W_BLOCKS) build W
__global__ __launch_bounds__(256) void prep_kernel(
        const float* __restrict__ x, const float* __restrict__ gamma,
        const float* __restrict__ beta, const float* __restrict__ sw,
        const float* __restrict__ bw, _Float16* __restrict__ A,
        _Float16* __restrict__ W) {
    if (blockIdx.x >= A_BLOCKS) {
        int idx = (blockIdx.x - A_BLOCKS) * 256 + threadIdx.x;  // one float4 each
        int o   = idx / 2304;
        int k4  = idx - o * 2304;
        float4 v;
        if (k4 < 2048) v = ((const float4*)sw)[(size_t)o * 2048 + k4];
        else           v = ((const float4*)bw)[(size_t)o * 256 + (k4 - 2048)];
        half4v h = { (_Float16)v.x, (_Float16)v.y, (_Float16)v.z, (_Float16)v.w };
        *(half4v*)(W + (size_t)idx * 4) = h;
        return;
    }
    const int wave = threadIdx.x >> 6, lane = threadIdx.x & 63;
    const int row = blockIdx.x * 4 + wave;
    const float* xr = x + (size_t)row * IN_F;

    float xv[16];
    float s = 0.0f, s2 = 0.0f;
#pragma unroll
    for (int j = 0; j < 16; ++j) {
        float v = xr[j * 64 + lane];
        xv[j] = v;
        s += v;
        s2 += v * v;
    }
#pragma unroll
    for (int off = 32; off > 0; off >>= 1) {
        s  += __shfl_xor(s, off);
        s2 += __shfl_xor(s2, off);
    }
    float mu   = s * (1.0f / IN_F);
    float var  = s2 * (1.0f / IN_F) - mu * mu;
    float rstd = rsqrtf(var + 1e-5f);

    const float cq[8] = {
        -2.0000000f * KC, -1.4285715f * KC, -0.8571429f * KC, -0.2857143f * KC,
         0.2857143f * KC,  0.8571429f * KC,  1.4285715f * KC,  2.0000000f * KC };

    _Float16* Arow = A + (size_t)row * KDIM;
    half8* basis_out = (half8*)Arow;                       // chunk f = feature f
    _Float16* silu_out = Arow + KSPLINE;
#pragma unroll
    for (int j = 0; j < 16; ++j) {
        int f = j * 64 + lane;
        float xs = xv[j];
        float xq = ((xs - mu) * rstd * gamma[f] + beta[f]) * KC;
        half8 h;
#pragma unroll
        for (int g = 0; g < 8; ++g) {
            float v = xq - cq[g];
            h[g] = (_Float16)exp2f(-(v * v));
        }
        basis_out[f] = h;
        silu_out[f] = (_Float16)(xs / (1.0f + exp2f(-xs * LOG2E)));
    }
}

// ---------------- GEMM: C(rows x 1024) = A(rows x 9216) * W^T + bias ----------
// m97 structure, 128x128 tile, BK=128 per barrier pair: four 128x32
// sub-buffers per operand (same banking as the verified BK=32 layout),
// barrier-drain events 288 (R5) -> 144 (R6) -> 72. LDS 64 KB, 2 blocks/CU
// (grid 512 = 2/CU, so occupancy is grid-pinned, not LDS-pinned).
__global__ __launch_bounds__(256, 2) void gemm_kernel(
        const _Float16* __restrict__ A, const _Float16* __restrict__ W,
        const float* __restrict__ bias, float* __restrict__ C) {
    __shared__ alignas(16) _Float16 As[4][128 * 32];   // 32 KB
    __shared__ alignas(16) _Float16 Bs[4][128 * 32];   // 32 KB
    const int bm = blockIdx.x, bn = blockIdx.y;
    const int tid = threadIdx.x;
    const int wave = tid >> 6, lane = tid & 63;
    const int wm = wave >> 1, wn = wave & 1;

    f32x4 acc[4][4] = {};

    // staging: per 128x32 sub-tile = 512 x 16B chunks; each wave 2 issues
    const _Float16* gAj[2];
    const _Float16* gBj[2];
    int ldsOff[2];
#pragma unroll
    for (int j = 0; j < 2; ++j) {
        int chunk = wave * 128 + j * 64 + lane;    // 0..511
        int r  = chunk >> 2;                       // tile row 0..127
        int c8 = (chunk & 3) * 8;                  // k-offset in elements
        gAj[j] = A + (size_t)(bm * 128 + r) * KDIM + c8;
        gBj[j] = W + (size_t)(bn * 128 + r) * KDIM + c8;
        ldsOff[j] = chunk * 8;                     // element offset in LDS sub-tile
    }

    const int lm = lane & 15;
    const int lk = (lane >> 4) * 8;

    for (int kt = 0; kt < KDIM / 128; ++kt) {
        __syncthreads();   // previous iter's ds_reads done before overwrite
#pragma unroll
        for (int h = 0; h < 4; ++h)
#pragma unroll
            for (int j = 0; j < 2; ++j) {
                __builtin_amdgcn_global_load_lds(
                    (const AS1 void*)(gAj[j] + kt * 128 + h * 32),
                    (AS3 void*)(&As[h][0] + ldsOff[j]), 16, 0, 0);
                __builtin_amdgcn_global_load_lds(
                    (const AS1 void*)(gBj[j] + kt * 128 + h * 32),
                    (AS3 void*)(&Bs[h][0] + ldsOff[j]), 16, 0, 0);
            }
        __syncthreads();   // staging complete

#pragma unroll
        for (int h = 0; h < 4; ++h) {
            half8 a[4], b[4];
#pragma unroll
            for (int i = 0; i < 4; ++i) {
                a[i] = *(const half8*)(&As[h][0] + (wm * 64 + i * 16 + lm) * 32 + lk);
                b[i] = *(const half8*)(&Bs[h][0] + (wn * 64 + i * 16 + lm) * 32 + lk);
            }
#pragma unroll
            for (int mi = 0; mi < 4; ++mi)
#pragma unroll
                for (int ni = 0; ni < 4; ++ni)
                    acc[mi][ni] = __builtin_amdgcn_mfma_f32_16x16x32_f16(
                        a[mi], b[ni], acc[mi][ni], 0, 0, 0);
        }
    }

    // epilogue: C/D layout col = lane&15, row = (lane>>4)*4 + reg
    const int cn = lane & 15;
    const int rm = (lane >> 4) * 4;
#pragma unroll
    for (int ni = 0; ni < 4; ++ni) {
        int col = bn * 128 + wn * 64 + ni * 16 + cn;
        float bv = bias[col];
#pragma unroll
        for (int mi = 0; mi < 4; ++mi) {
            int row = bm * 128 + wm * 64 + mi * 16 + rm;
            float* Cp = C + (size_t)row * OUT_F + col;
#pragma unroll
            for (int r = 0; r < 4; ++r)
                Cp[(size_t)r * OUT_F] = acc[mi][ni][r] + bv;
        }
    }
}

extern "C" void kernel_launch(void* const* d_in, const int* in_sizes, int n_in,
                              void* d_out, int out_size, void* d_ws, size_t ws_size,
                              hipStream_t stream) {
    const float* x     = (const float*)d_in[0];
    const float* gamma = (const float*)d_in[1];
    const float* beta  = (const float*)d_in[2];
    const float* sw    = (const float*)d_in[3];
    const float* bw    = (const float*)d_in[4];
    const float* bb    = (const float*)d_in[5];
    float* out = (float*)d_out;

    char* ws = (char*)d_ws;
    _Float16* Wb = (_Float16*)ws;                                 // 18.9 MB
    _Float16* Ab = (_Float16*)(ws + (size_t)OUT_F * KDIM * 2);    // 151 MB

    prep_kernel<<<A_BLOCKS + W_BLOCKS, 256, 0, stream>>>(
        x, gamma, beta, sw, bw, Ab, Wb);
    gemm_kernel<<<dim3(M_ROWS / 128, OUT_F / 128), 256, 0, stream>>>(
        Ab, Wb, bb, out);
}